// Round 4
// baseline (1769.378 us; speedup 1.0000x reference)
//
#include <hip/hip_runtime.h>

// Problem constants
#define BD (1024LL * 1024LL)   // B*D elements per node-plane

using bf16x8 = __attribute__((ext_vector_type(8))) __bf16;
using f32x4  = __attribute__((ext_vector_type(4))) float;

__device__ __forceinline__ unsigned short f2bf(float f) {
  unsigned int u = __float_as_uint(f);
  u += 0x7fffu + ((u >> 16) & 1u);   // RNE
  return (unsigned short)(u >> 16);
}
__device__ __forceinline__ float bf2f(unsigned short h) {
  return __uint_as_float((unsigned int)h << 16);
}

// async global->LDS, 16B per lane; lds ptr wave-uniform, lanes land at +lane*16
__device__ __forceinline__ void gl_lds16(const unsigned short* g, unsigned short* l) {
  __builtin_amdgcn_global_load_lds(
      (const __attribute__((address_space(1))) void*)g,
      (__attribute__((address_space(3))) void*)l, 16, 0, 0);
}

// ---------------------------------------------------------------------------
// Fused preamble: 5 fp32->bf16 weight converts + state init, one dispatch.
// Segment block ranges (each block = 1024 elems): o_w 9216 | w1_s 10240 |
// w2_s 10240 | w1_e 32768 | w2_e 32768 | init 13312 (13*BD floats as float4).
__global__ __launch_bounds__(256) void preamble_kernel(
    const float* __restrict__ o_w,  unsigned short* __restrict__ wo,
    const float* __restrict__ w1_s, unsigned short* __restrict__ w1s,
    const float* __restrict__ w2_s, unsigned short* __restrict__ w2s,
    const float* __restrict__ w1_e, unsigned short* __restrict__ w1e,
    const float* __restrict__ w2_e, unsigned short* __restrict__ w2e,
    const float* __restrict__ seed, float* __restrict__ S,
    float* __restrict__ mem) {
  long long b = blockIdx.x;
  const float* src;
  unsigned short* dst;
  if (b < 9216)       { src = o_w;  dst = wo; }
  else if (b < 19456) { src = w1_s; dst = w1s; b -= 9216; }
  else if (b < 29696) { src = w2_s; dst = w2s; b -= 19456; }
  else if (b < 62464) { src = w1_e; dst = w1e; b -= 29696; }
  else if (b < 95232) { src = w2_e; dst = w2e; b -= 62464; }
  else {
    // init: S = 0 except node 4 = seed; mem = 0
    long long i = (b - 95232) * 256 + threadIdx.x;  // float4 index
    const long long S4 = 9 * BD / 4;
    if (i < S4) {
      float4 v = make_float4(0.f, 0.f, 0.f, 0.f);
      const long long lo4 = 4 * BD / 4, hi4 = 5 * BD / 4;
      if (i >= lo4 && i < hi4) v = *(const float4*)(seed + (i - lo4) * 4);
      *(float4*)(S + i * 4) = v;
    } else {
      *(float4*)(mem + (i - S4) * 4) = make_float4(0.f, 0.f, 0.f, 0.f);
    }
    return;
  }
  long long i = b * 256 + threadIdx.x;
  float4 v = *(const float4*)(src + i * 4);
  unsigned int lo = (unsigned int)f2bf(v.x) | ((unsigned int)f2bf(v.y) << 16);
  unsigned int hi = (unsigned int)f2bf(v.z) | ((unsigned int)f2bf(v.w) << 16);
  *(uint2*)(dst + i * 4) = make_uint2(lo, hi);
}

// ---------------------------------------------------------------------------
// Transposing cvt: dst[n][j][k] (bf16) = src[n][k][j] (fp32), 1024x1024 per node
__global__ __launch_bounds__(256) void tcvt_kernel(const float* __restrict__ src,
                                                   unsigned short* __restrict__ dst) {
  __shared__ float tile[32][33];
  const int n = blockIdx.z;
  const int bk = blockIdx.y * 32;
  const int bj = blockIdx.x * 32;
  const int tx = threadIdx.x & 31;
  const int ty = threadIdx.x >> 5;
#pragma unroll
  for (int r = 0; r < 4; ++r)
    tile[ty + r * 8][tx] = src[(long long)n * BD + (long long)(bk + ty + r * 8) * 1024 + bj + tx];
  __syncthreads();
#pragma unroll
  for (int r = 0; r < 4; ++r)
    dst[(long long)n * BD + (long long)(bj + ty + r * 8) * 1024 + bk + tx] =
        f2bf(tile[tx][ty + r * 8]);
}

// ---------------------------------------------------------------------------
// Combined attention bias: cb[n][i] = o_b[n][i] + sum_k o_w[n][i][k] * v_b[n][k]
__global__ __launch_bounds__(256) void cb_kernel(const float* __restrict__ o_w,
                                                 const float* __restrict__ v_b,
                                                 const float* __restrict__ o_b,
                                                 float* __restrict__ cb) {
  const int n = blockIdx.y;
  const int i = blockIdx.x * 4 + (threadIdx.x >> 6);
  const int lane = threadIdx.x & 63;
  const float* row = o_w + (long long)n * BD + (long long)i * 1024;
  const float* vb = v_b + n * 1024;
  float s = 0.f;
#pragma unroll
  for (int t = 0; t < 16; ++t) s += row[lane + t * 64] * vb[lane + t * 64];
  for (int off = 32; off > 0; off >>= 1) s += __shfl_down(s, off);
  if (lane == 0) cb[n * 1024 + i] = o_b[n * 1024 + i] + s;
}

// ---------------------------------------------------------------------------
// LayerNorm over D=1024, one (node,row) per 256-thread block.
// ADJ=true: input = neighbor-sum of S (3x3 grid), also writes integ (fp32).
template <bool ADJ>
__global__ __launch_bounds__(256) void ln_kernel(const float* __restrict__ in,
                                                 const float* __restrict__ gam,
                                                 const float* __restrict__ bet,
                                                 float* __restrict__ integ,
                                                 unsigned short* __restrict__ out) {
  const int row = blockIdx.x;
  const int node = blockIdx.y;
  const int tid = threadIdx.x;
  const long long rowoff = (long long)row * 1024 + tid * 4;
  const long long base = (long long)node * BD + rowoff;
  float4 v;
  if (ADJ) {
    v = make_float4(0.f, 0.f, 0.f, 0.f);
    const int r = node / 3, c = node % 3;
    if (r > 0) { float4 t = *(const float4*)(in + (node - 3) * BD + rowoff); v.x += t.x; v.y += t.y; v.z += t.z; v.w += t.w; }
    if (r < 2) { float4 t = *(const float4*)(in + (node + 3) * BD + rowoff); v.x += t.x; v.y += t.y; v.z += t.z; v.w += t.w; }
    if (c > 0) { float4 t = *(const float4*)(in + (node - 1) * BD + rowoff); v.x += t.x; v.y += t.y; v.z += t.z; v.w += t.w; }
    if (c < 2) { float4 t = *(const float4*)(in + (node + 1) * BD + rowoff); v.x += t.x; v.y += t.y; v.z += t.z; v.w += t.w; }
    *(float4*)(integ + base) = v;
  } else {
    v = *(const float4*)(in + base);
  }
  float s = v.x + v.y + v.z + v.w;
  float q = v.x * v.x + v.y * v.y + v.z * v.z + v.w * v.w;
  for (int off = 32; off > 0; off >>= 1) {
    s += __shfl_down(s, off);
    q += __shfl_down(q, off);
  }
  __shared__ float red[8];
  if ((tid & 63) == 0) { red[tid >> 6] = s; red[4 + (tid >> 6)] = q; }
  __syncthreads();
  s = red[0] + red[1] + red[2] + red[3];
  q = red[4] + red[5] + red[6] + red[7];
  const float mean = s * (1.0f / 1024.0f);
  const float var = q * (1.0f / 1024.0f) - mean * mean;
  const float inv = rsqrtf(var + 1e-5f);
  const float4 g = *(const float4*)(gam + node * 1024 + tid * 4);
  const float4 b = *(const float4*)(bet + node * 1024 + tid * 4);
  const float o0 = (v.x - mean) * inv * g.x + b.x;
  const float o1 = (v.y - mean) * inv * g.y + b.y;
  const float o2 = (v.z - mean) * inv * g.z + b.z;
  const float o3 = (v.w - mean) * inv * g.w + b.w;
  unsigned int lo = (unsigned int)f2bf(o0) | ((unsigned int)f2bf(o1) << 16);
  unsigned int hi = (unsigned int)f2bf(o2) | ((unsigned int)f2bf(o3) << 16);
  *(uint2*)(out + base) = make_uint2(lo, hi);
}

// ---------------------------------------------------------------------------
// Shared GEMM core: 128x128 tile, BK=64 (2 x 32-k panels), 4 waves of 64x64,
// 16x16x32 bf16 MFMA, global_load_lds(16B), XOR-swizzled LDS (conflict-free).
// 32 MFMA per barrier pair.  LDS: 2 x 16 KB.
__device__ __forceinline__ void gemm_core64(
    const unsigned short* __restrict__ Xz, const unsigned short* __restrict__ Wz,
    long long bm, long long bn, int K, int kbeg, int kend,
    unsigned short* Als, unsigned short* Bls, f32x4 acc[4][4]) {
  const int tid = threadIdx.x;
  const int lane = tid & 63;
  const int wid = tid >> 6;
  const int wm = (wid >> 1) * 64;
  const int wn = (wid & 1) * 64;
  const int lm = lane & 15;
  const int quad = lane >> 4;
  const int lrow = lane >> 2;
  const int gch = ((lane & 3) ^ ((lane >> 3) & 3)) * 8;  // swizzled k-chunk (global)
  const int fch = (quad ^ ((lm >> 1) & 3)) * 8;          // fragment-read chunk

  for (int k0 = kbeg; k0 < kend; k0 += 64) {
    __syncthreads();
#pragma unroll
    for (int p = 0; p < 2; ++p)
#pragma unroll
      for (int t = 0; t < 2; ++t) {
        const int idx = wid * 2 + t;
        const long long row = idx * 16 + lrow;
        gl_lds16(Xz + (bm + row) * K + k0 + p * 32 + gch, &Als[p * 4096 + idx * 512]);
        gl_lds16(Wz + (bn + row) * K + k0 + p * 32 + gch, &Bls[p * 4096 + idx * 512]);
      }
    __syncthreads();
#pragma unroll
    for (int p = 0; p < 2; ++p) {
      bf16x8 af[4], bfv[4];
#pragma unroll
      for (int i = 0; i < 4; ++i)
        af[i] = *(const bf16x8*)&Als[p * 4096 + (wm + i * 16 + lm) * 32 + fch];
#pragma unroll
      for (int j = 0; j < 4; ++j)
        bfv[j] = *(const bf16x8*)&Bls[p * 4096 + (wn + j * 16 + lm) * 32 + fch];
#pragma unroll
      for (int i = 0; i < 4; ++i)
#pragma unroll
        for (int j = 0; j < 4; ++j)
          acc[i][j] = __builtin_amdgcn_mfma_f32_16x16x32_bf16(af[i], bfv[j], acc[i][j], 0, 0, 0);
    }
  }
}

// C/D layout: col = lane&15, row = quad*4 + reg  (HW-verified)
__device__ __forceinline__ void store_bf16_tile(
    unsigned short* out, int N, long long bm, long long bn,
    const float* bias, bool relu, f32x4 acc[4][4]) {
  const int tid = threadIdx.x;
  const int lane = tid & 63;
  const int wid = tid >> 6;
  const int wm = (wid >> 1) * 64;
  const int wn = (wid & 1) * 64;
  const int lm = lane & 15;
  const int quad = lane >> 4;
#pragma unroll
  for (int i = 0; i < 4; ++i) {
    const long long rb = bm + wm + i * 16 + quad * 4;
#pragma unroll
    for (int j = 0; j < 4; ++j) {
      const int col = (int)bn + wn + j * 16 + lm;
      const float bv = bias ? bias[col] : 0.0f;
#pragma unroll
      for (int r = 0; r < 4; ++r) {
        float v = acc[i][j][r] + bv;
        if (relu) v = fmaxf(v, 0.0f);
        out[(rb + r) * (long long)N + col] = f2bf(v);
      }
    }
  }
}

// ---------------------------------------------------------------------------
// Attention GEMM: S[n] = integ[n] + xn[n] @ wc[n]^T + cb[n]; memory-node EMA.
// grid (8, 8, 9)
__global__ __launch_bounds__(256, 4) void attn_kernel(
    const unsigned short* __restrict__ xn, const unsigned short* __restrict__ wc,
    const float* __restrict__ cb, const float* __restrict__ integ,
    float* __restrict__ memio, float* __restrict__ S) {
  __shared__ unsigned short Als[128 * 64];
  __shared__ unsigned short Bls[128 * 64];
  const int node = blockIdx.z;
  const long long bm = (long long)blockIdx.y * 128;
  const long long bn = (long long)blockIdx.x * 128;
  f32x4 acc[4][4] = {};
  gemm_core64(xn + (long long)node * BD, wc + (long long)node * BD,
              bm, bn, 1024, 0, 1024, Als, Bls, acc);

  const int tid = threadIdx.x;
  const int lane = tid & 63;
  const int wid = tid >> 6;
  const int wm = (wid >> 1) * 64;
  const int wn = (wid & 1) * 64;
  const int lm = lane & 15;
  const int quad = lane >> 4;
  const float* bz = cb + node * 1024;
  float* out = S + (long long)node * BD;
  const float* az = integ + (long long)node * BD;
  const bool is_mem = (node != 4) && ((node & 1) == 0);
  float* mz = nullptr;
  if (is_mem) {
    const int mi = (node == 0) ? 0 : (node == 2) ? 1 : (node == 6) ? 2 : 3;
    mz = memio + (long long)mi * BD;
  }
#pragma unroll
  for (int i = 0; i < 4; ++i) {
    const long long rb = bm + wm + i * 16 + quad * 4;
#pragma unroll
    for (int j = 0; j < 4; ++j) {
      const int col = (int)bn + wn + j * 16 + lm;
      const float bv = bz[col];
#pragma unroll
      for (int r = 0; r < 4; ++r) {
        const long long idx = (rb + r) * 1024LL + col;
        float v = acc[i][j][r] + bv + az[idx];
        if (is_mem) {
          v = 0.7f * mz[idx] + 0.3f * v;
          mz[idx] = v;
        }
        out[idx] = v;
      }
    }
  }
}

// ---------------------------------------------------------------------------
// wc precompute: wc[n] = wo[n] @ vwT[n]^T (bf16 out, no bias).  grid (8,8,9)
__global__ __launch_bounds__(256, 4) void wcg_kernel(
    const unsigned short* __restrict__ wo, const unsigned short* __restrict__ vwT,
    unsigned short* __restrict__ wc) {
  __shared__ unsigned short Als[128 * 64];
  __shared__ unsigned short Bls[128 * 64];
  const int node = blockIdx.z;
  const long long bm = (long long)blockIdx.y * 128;
  const long long bn = (long long)blockIdx.x * 128;
  f32x4 acc[4][4] = {};
  gemm_core64(wo + (long long)node * BD, vwT + (long long)node * BD,
              bm, bn, 1024, 0, 1024, Als, Bls, acc);
  store_bf16_tile(wc + (long long)node * BD, 1024, bm, bn, nullptr, false, acc);
}

// ---------------------------------------------------------------------------
// FFN layer 1 (both roles in one dispatch): relu(xn2 @ w1^T + b1) -> h (bf16)
// 1-D grid 2688: [0,640) small (5 nodes x 16bn x 8bm), [640,2688) expert (4 x 64bn x 8bm)
__global__ __launch_bounds__(256, 4) void ffn1_kernel(
    const unsigned short* __restrict__ xn,
    const unsigned short* __restrict__ w1s, const float* __restrict__ b1s,
    const unsigned short* __restrict__ w1e, const float* __restrict__ b1e,
    unsigned short* __restrict__ hs, unsigned short* __restrict__ he) {
  __shared__ unsigned short Als[128 * 64];
  __shared__ unsigned short Bls[128 * 64];
  const int id = blockIdx.x;
  const unsigned short *X, *W;
  const float* bias;
  unsigned short* out;
  int N, t;
  if (id < 640) {
    const int si = id >> 7;
    t = id & 127;
    X = xn + (long long)si * 2 * BD;
    W = w1s + (long long)si * 2 * BD;
    bias = b1s + si * 2048;
    out = hs + (long long)si * 2 * BD;
    N = 2048;
  } else {
    const int id2 = id - 640;
    const int e = id2 >> 9;
    t = id2 & 511;
    X = xn + BD + (long long)e * 2 * BD;
    W = w1e + (long long)e * 8 * BD;
    bias = b1e + e * 8192;
    out = he + (long long)e * 8 * BD;
    N = 8192;
  }
  const long long bm = (long long)(t & 7) * 128;
  const long long bn = (long long)(t >> 3) * 128;
  f32x4 acc[4][4] = {};
  gemm_core64(X, W, bm, bn, 1024, 0, 1024, Als, Bls, acc);
  store_bf16_tile(out, N, bm, bn, bias, true, acc);
}

// ---------------------------------------------------------------------------
// FFN layer 2 split-K partials (both roles): part = h @ w2^T (bf16, no bias)
// 1-D grid 1664: [0,640) small (z=si*2+kz, 64 tiles), [640,1664) expert (z=e*4+kz)
__global__ __launch_bounds__(256, 4) void ffn2p_kernel(
    const unsigned short* __restrict__ hs, const unsigned short* __restrict__ w2s,
    const unsigned short* __restrict__ he, const unsigned short* __restrict__ w2e,
    unsigned short* __restrict__ part_s, unsigned short* __restrict__ part_e) {
  __shared__ unsigned short Als[128 * 64];
  __shared__ unsigned short Bls[128 * 64];
  const int id = blockIdx.x;
  const unsigned short *X, *W;
  unsigned short* out;
  int K, kbeg, kend, t;
  if (id < 640) {
    const int z = id >> 6;
    t = id & 63;
    const int si = z >> 1, kz = z & 1;
    X = hs + (long long)si * 2 * BD;
    W = w2s + (long long)si * 2 * BD;
    K = 2048; kbeg = kz * 1024; kend = kbeg + 1024;
    out = part_s + (long long)z * BD;
  } else {
    const int id2 = id - 640;
    const int z = id2 >> 6;
    t = id2 & 63;
    const int e = z >> 2, kz = z & 3;
    X = he + (long long)e * 8 * BD;
    W = w2e + (long long)e * 8 * BD;
    K = 8192; kbeg = kz * 2048; kend = kbeg + 2048;
    out = part_e + (long long)z * BD;
  }
  const long long bm = (long long)(t >> 3) * 128;
  const long long bn = (long long)(t & 7) * 128;
  f32x4 acc[4][4] = {};
  gemm_core64(X, W, bm, bn, K, kbeg, kend, Als, Bls, acc);
  store_bf16_tile(out, 1024, bm, bn, nullptr, false, acc);
}

// ---------------------------------------------------------------------------
// Split-K reduce: S[node] += sum_kz partial[kz] + bias.  bf16 partials.
__global__ __launch_bounds__(256) void reduce_kernel(const unsigned short* __restrict__ part_s,
                                                     const unsigned short* __restrict__ part_e,
                                                     const float* __restrict__ b2s,
                                                     const float* __restrict__ b2e,
                                                     float* __restrict__ S) {
  const int node = blockIdx.y;
  const long long i8 = ((long long)blockIdx.x * 256 + threadIdx.x) * 8;
  const int col = (int)(i8 & 1023);
  const unsigned short* base;
  const float* bias;
  int SKn;
  if (node & 1) {
    const int e = (node - 1) >> 1;
    base = part_e + (long long)(e * 4) * BD + i8;
    bias = b2e + e * 1024;
    SKn = 4;
  } else {
    const int si = node >> 1;
    base = part_s + (long long)(si * 2) * BD + i8;
    bias = b2s + si * 1024;
    SKn = 2;
  }
  float sum[8] = {};
  for (int kz = 0; kz < SKn; ++kz) {
    uint4 p = *(const uint4*)(base + (long long)kz * BD);
    const unsigned short* ph = (const unsigned short*)&p;
#pragma unroll
    for (int j = 0; j < 8; ++j) sum[j] += bf2f(ph[j]);
  }
  float* sp = S + (long long)node * BD + i8;
  float4 s0 = *(float4*)sp;
  float4 s1 = *(float4*)(sp + 4);
  s0.x += sum[0] + bias[col + 0];
  s0.y += sum[1] + bias[col + 1];
  s0.z += sum[2] + bias[col + 2];
  s0.w += sum[3] + bias[col + 3];
  s1.x += sum[4] + bias[col + 4];
  s1.y += sum[5] + bias[col + 5];
  s1.z += sum[6] + bias[col + 6];
  s1.w += sum[7] + bias[col + 7];
  *(float4*)sp = s0;
  *(float4*)(sp + 4) = s1;
}

// ---------------------------------------------------------------------------
extern "C" void kernel_launch(void* const* d_in, const int* in_sizes, int n_in,
                              void* d_out, int out_size, void* d_ws, size_t ws_size,
                              hipStream_t stream) {
  const float* seed  = (const float*)d_in[0];
  const float* ln1_s = (const float*)d_in[1];
  const float* ln1_b = (const float*)d_in[2];
  const float* v_w   = (const float*)d_in[3];
  const float* v_b   = (const float*)d_in[4];
  const float* o_w   = (const float*)d_in[5];
  const float* o_b   = (const float*)d_in[6];
  const float* ln2_s = (const float*)d_in[7];
  const float* ln2_b = (const float*)d_in[8];
  const float* w1_s  = (const float*)d_in[9];
  const float* b1_s  = (const float*)d_in[10];
  const float* w2_s  = (const float*)d_in[11];
  const float* b2_s  = (const float*)d_in[12];
  const float* w1_e  = (const float*)d_in[13];
  const float* b1_e  = (const float*)d_in[14];
  const float* w2_e  = (const float*)d_in[15];
  const float* b2_e  = (const float*)d_in[16];

  char* ws = (char*)d_ws;
  size_t off = 0;
  auto alloc = [&](long long elems, int esize) {
    void* p = ws + off;
    off += (size_t)((elems * esize + 255LL) & ~255LL);
    return p;
  };
  unsigned short* wo    = (unsigned short*)alloc(9 * BD, 2);
  unsigned short* vwT   = (unsigned short*)alloc(9 * BD, 2);
  unsigned short* wc    = (unsigned short*)alloc(9 * BD, 2);
  unsigned short* w1s   = (unsigned short*)alloc(10 * BD, 2);
  unsigned short* w2s   = (unsigned short*)alloc(10 * BD, 2);
  unsigned short* w1e   = (unsigned short*)alloc(32 * BD, 2);
  unsigned short* w2e   = (unsigned short*)alloc(32 * BD, 2);
  float*          membuf= (float*)alloc(4 * BD, 4);
  float*          cb    = (float*)alloc(9 * 1024, 4);
  // union region: {integ fp32 + xn bf16} (54 MB)  <->  {part_s + part_e} (52 MB)
  char* region = (char*)alloc(9 * BD * 4 + 9 * BD * 2, 1);
  float*          integ  = (float*)region;
  unsigned short* xn     = (unsigned short*)(region + 9 * BD * 4);
  unsigned short* part_s = (unsigned short*)region;                 // 10 planes bf16
  unsigned short* part_e = (unsigned short*)(region + 10 * BD * 2); // 16 planes bf16
  unsigned short* hs    = (unsigned short*)alloc(10 * BD, 2);
  unsigned short* he    = (unsigned short*)alloc(32 * BD, 2);

  float* S = (float*)d_out;  // S lives in d_out; also aliases x within a step

  // One-time (per launch): weight conversion + init (fused), vwT, cb, wc
  preamble_kernel<<<108544, 256, 0, stream>>>(o_w, wo, w1_s, w1s, w2_s, w2s,
                                              w1_e, w1e, w2_e, w2e, seed, S, membuf);
  tcvt_kernel<<<dim3(32, 32, 9), 256, 0, stream>>>(v_w, vwT);
  cb_kernel<<<dim3(256, 9), 256, 0, stream>>>(o_w, v_b, o_b, cb);
  wcg_kernel<<<dim3(8, 8, 9), 256, 0, stream>>>(wo, vwT, wc);

  for (int step = 0; step < 3; ++step) {
    // integ = A@S ; xn = LN1(integ)
    ln_kernel<true><<<dim3(1024, 9), 256, 0, stream>>>(S, ln1_s, ln1_b, integ, xn);
    // x = integ + xn @ wc^T + cb ; memory-node EMA; writes S(=x) and mem
    attn_kernel<<<dim3(8, 8, 9), 256, 0, stream>>>(xn, wc, cb, integ, membuf, S);
    // xn2 = LN2(x)
    ln_kernel<false><<<dim3(1024, 9), 256, 0, stream>>>(S, ln2_s, ln2_b, nullptr, xn);
    // hs/he = relu(xn2 @ w1^T + b1)   (one dispatch, both roles)
    ffn1_kernel<<<2688, 256, 0, stream>>>(xn, w1s, b1_s, w1e, b1_e, hs, he);
    // part_s/part_e = split-K partials of h @ w2^T   (one dispatch)
    ffn2p_kernel<<<1664, 256, 0, stream>>>(hs, w2s, he, w2e, part_s, part_e);
    // S += sum(partials) + b2
    reduce_kernel<<<dim3(512, 9), 256, 0, stream>>>(part_s, part_e, b2_s, b2_e, S);
  }
}